// Round 1
// 641.437 us; speedup vs baseline: 3.4997x; 3.4997x over previous
//
#include <hip/hip_runtime.h>
#include <cstdio>

// ---------------------------------------------------------------------------
// GraphMessagePassing, f32. k-outer micro-GEMM restructure:
//  - each wave owns EPG=16 edges (or nodes), stages input rows into a
//    per-wave LDS tile via coalesced 256B loads
//  - weights streamed k-outer: one 256B coalesced weight load feeds 16 FMAs
//    (weight L1 traffic drops 36KB/edge -> 2.25KB/edge)
//  - activations broadcast from LDS with ds_read_b128 (same-addr = no bank
//    conflict); layer1->layer2 transpose reuses the same tile (no __shfl)
// ---------------------------------------------------------------------------

#define EPG 16       // edges/nodes per wave
#define WPB 4        // waves per block
#define THREADS 256

__global__ void zero_ws(float* __restrict__ p, int n) {
    int i = blockIdx.x * blockDim.x + threadIdx.x;
    if (i < n) p[i] = 0.0f;
}

// Edge phase: h = relu(b1 + [node[src], edge_feat] @ w1); m = b2 + h @ w2;
// atomicAdd m into agg[dst].
__launch_bounds__(THREADS, 4)
__global__ void GraphMessagePassing_5952824672257_kernel(
    const float* __restrict__ nodef,   // [N,64]
    const float* __restrict__ edgef,   // [E,16]
    const int*   __restrict__ eidx,    // [2,E] int32
    const float* __restrict__ w1,      // [80,64] row-major
    const float* __restrict__ b1,      // [64]
    const float* __restrict__ w2,      // [64,64]
    const float* __restrict__ b2,      // [64]
    float* __restrict__ agg,           // [N,64] pre-zeroed
    int n_edges, int n_nodes)
{
    __shared__ __align__(16) float Alds[WPB][EPG][80];
    const int lane = threadIdx.x & 63;
    const int wid  = threadIdx.x >> 6;
    float* A = &Alds[wid][0][0];

    const long gid = (long)blockIdx.x * WPB + wid;
    long base = gid * (long)EPG;
    const bool active = base < n_edges;           // grid-tail duplicate waves
    if (!active) base = (long)n_edges - EPG;      // re-stage last group, no atomics
    if (base < 0) base = 0;

    // edge indices: lanes 0-15 carry the 16 edges (replicated x4, one segment)
    long ib = base + (lane & 15);
    if (ib >= n_edges) ib = n_edges - 1;
    const int tmp_s = eidx[ib];
    const int tmp_d = eidx[(size_t)n_edges + ib];

    // ---- stage source-node rows (coalesced 256B gathers, SGPR row base)
    #pragma unroll
    for (int e = 0; e < EPG; ++e) {
        int s = __builtin_amdgcn_readlane(tmp_s, e);
        if ((unsigned)s >= (unsigned)n_nodes) s = 0;   // safety clamp
        A[e * 80 + lane] = nodef[(size_t)s * 64 + lane];
    }
    // ---- stage edge features: 16 edges x 16 f32 = 256 contiguous floats
    {
        size_t fi = (size_t)base * 16 + (size_t)lane * 4;
        float4 v = make_float4(0.f, 0.f, 0.f, 0.f);
        if (fi + 3 < (size_t)n_edges * 16) v = *(const float4*)(edgef + fi);
        *(float4*)&A[(lane >> 2) * 80 + 64 + (lane & 3) * 4] = v;
    }
    __syncthreads();

    // ---- layer 1: k-outer, 1 weight load : 16 FMAs
    const float b1v = b1[lane];
    float h[EPG];
    #pragma unroll
    for (int e = 0; e < EPG; ++e) h[e] = b1v;
    for (int kc = 0; kc < 80; kc += 4) {
        const float wa = w1[(kc + 0) * 64 + lane];
        const float wb = w1[(kc + 1) * 64 + lane];
        const float wc = w1[(kc + 2) * 64 + lane];
        const float wd = w1[(kc + 3) * 64 + lane];
        #pragma unroll
        for (int e = 0; e < EPG; ++e) {
            const float4 a = *(const float4*)&A[e * 80 + kc];  // broadcast read
            h[e] = fmaf(a.x, wa, h[e]);
            h[e] = fmaf(a.y, wb, h[e]);
            h[e] = fmaf(a.z, wc, h[e]);
            h[e] = fmaf(a.w, wd, h[e]);
        }
    }
    __syncthreads();

    // ---- relu + transpose through LDS (reuse tile rows; per-wave region)
    #pragma unroll
    for (int e = 0; e < EPG; ++e)
        A[e * 80 + lane] = fmaxf(h[e], 0.f);
    __syncthreads();

    // ---- layer 2
    const float b2v = b2[lane];
    float m[EPG];
    #pragma unroll
    for (int e = 0; e < EPG; ++e) m[e] = b2v;
    for (int tc = 0; tc < 64; tc += 4) {
        const float ua = w2[(tc + 0) * 64 + lane];
        const float ub = w2[(tc + 1) * 64 + lane];
        const float uc = w2[(tc + 2) * 64 + lane];
        const float ud = w2[(tc + 3) * 64 + lane];
        #pragma unroll
        for (int e = 0; e < EPG; ++e) {
            const float4 a = *(const float4*)&A[e * 80 + tc];
            m[e] = fmaf(a.x, ua, m[e]);
            m[e] = fmaf(a.y, ub, m[e]);
            m[e] = fmaf(a.z, uc, m[e]);
            m[e] = fmaf(a.w, ud, m[e]);
        }
    }

    // ---- scatter-add (coalesced 256B atomic per edge)
    #pragma unroll
    for (int e = 0; e < EPG; ++e) {
        if (active && base + e < n_edges) {
            int d = __builtin_amdgcn_readlane(tmp_d, e);
            if ((unsigned)d < (unsigned)n_nodes)
                atomicAdd(agg + (size_t)d * 64 + lane, m[e]);
        }
    }
}

// Node phase: out = relu(b1 + [node, agg] @ w_u1) @ w_u2 + b_u2
__launch_bounds__(THREADS, 4)
__global__ void node_mlp_tiled(
    const float* __restrict__ nodef,   // [N,64]
    const float* __restrict__ agg,     // [N,64]
    const float* __restrict__ w1,      // [128,64]
    const float* __restrict__ b1,      // [64]
    const float* __restrict__ w2,      // [64,64]
    const float* __restrict__ b2,      // [64]
    float* __restrict__ out,           // [N,64]
    int n_nodes)
{
    __shared__ __align__(16) float Alds[WPB][EPG][128];
    const int lane = threadIdx.x & 63;
    const int wid  = threadIdx.x >> 6;
    float* A = &Alds[wid][0][0];

    const long gid = (long)blockIdx.x * WPB + wid;
    long base = gid * (long)EPG;
    const bool active = base < n_nodes;
    if (!active) base = (long)n_nodes - EPG;
    if (base < 0) base = 0;

    // ---- stage [node | agg] rows (consecutive rows -> fully coalesced)
    #pragma unroll
    for (int e = 0; e < EPG; ++e) {
        size_t r = (size_t)base + e;
        if (r >= (size_t)n_nodes) r = n_nodes - 1;
        A[e * 128 + lane]      = nodef[r * 64 + lane];
        A[e * 128 + 64 + lane] = agg[r * 64 + lane];
    }
    __syncthreads();

    // ---- layer 1 (128-dim input)
    const float b1v = b1[lane];
    float h[EPG];
    #pragma unroll
    for (int e = 0; e < EPG; ++e) h[e] = b1v;
    for (int kc = 0; kc < 128; kc += 4) {
        const float wa = w1[(kc + 0) * 64 + lane];
        const float wb = w1[(kc + 1) * 64 + lane];
        const float wc = w1[(kc + 2) * 64 + lane];
        const float wd = w1[(kc + 3) * 64 + lane];
        #pragma unroll
        for (int e = 0; e < EPG; ++e) {
            const float4 a = *(const float4*)&A[e * 128 + kc];
            h[e] = fmaf(a.x, wa, h[e]);
            h[e] = fmaf(a.y, wb, h[e]);
            h[e] = fmaf(a.z, wc, h[e]);
            h[e] = fmaf(a.w, wd, h[e]);
        }
    }
    __syncthreads();

    #pragma unroll
    for (int e = 0; e < EPG; ++e)
        A[e * 128 + lane] = fmaxf(h[e], 0.f);
    __syncthreads();

    // ---- layer 2
    const float b2v = b2[lane];
    float m[EPG];
    #pragma unroll
    for (int e = 0; e < EPG; ++e) m[e] = b2v;
    for (int tc = 0; tc < 64; tc += 4) {
        const float ua = w2[(tc + 0) * 64 + lane];
        const float ub = w2[(tc + 1) * 64 + lane];
        const float uc = w2[(tc + 2) * 64 + lane];
        const float ud = w2[(tc + 3) * 64 + lane];
        #pragma unroll
        for (int e = 0; e < EPG; ++e) {
            const float4 a = *(const float4*)&A[e * 128 + tc];
            m[e] = fmaf(a.x, ua, m[e]);
            m[e] = fmaf(a.y, ub, m[e]);
            m[e] = fmaf(a.z, uc, m[e]);
            m[e] = fmaf(a.w, ud, m[e]);
        }
    }

    #pragma unroll
    for (int e = 0; e < EPG; ++e) {
        if (active && base + e < n_nodes)
            out[((size_t)base + e) * 64 + lane] = m[e];
    }
}

extern "C" void kernel_launch(void* const* d_in, const int* in_sizes, int n_in,
                              void* d_out, int out_size, void* d_ws, size_t ws_size,
                              hipStream_t stream) {
    // setup_inputs() order:
    // 0 node_features[N,64] f32, 1 edge_features[E,16] f32, 2 edge_index[2,E] i32,
    // 3 w_m1[80,64], 4 b_m1, 5 w_m2[64,64], 6 b_m2,
    // 7 w_u1[128,64], 8 b_u1, 9 w_u2[64,64], 10 b_u2   (all f32)
    const float* nodef = (const float*)d_in[0];
    const float* edgef = (const float*)d_in[1];
    const int*   eidx  = (const int*)d_in[2];
    const float* w_m1  = (const float*)d_in[3];
    const float* b_m1  = (const float*)d_in[4];
    const float* w_m2  = (const float*)d_in[5];
    const float* b_m2  = (const float*)d_in[6];
    const float* w_u1  = (const float*)d_in[7];
    const float* b_u1  = (const float*)d_in[8];
    const float* w_u2  = (const float*)d_in[9];
    const float* b_u2  = (const float*)d_in[10];
    float* out = (float*)d_out;

    const int n_nodes = out_size / 64;
    const int n_edges = in_sizes[2] / 2;

    fprintf(stderr, "[KL] f32 tiled pipeline E=%d N=%d ws=%zu\n",
            n_edges, n_nodes, ws_size);
    fflush(stderr);

    // agg[N,64] f32 in workspace (12.8 MB; ws is 320 MB)
    float* agg = (float*)d_ws;
    const int zn = n_nodes * 64;
    zero_ws<<<(zn + THREADS - 1) / THREADS, THREADS, 0, stream>>>(agg, zn);

    const int groups_e = (n_edges + EPG - 1) / EPG;
    const int blocks_e = (groups_e + WPB - 1) / WPB;
    GraphMessagePassing_5952824672257_kernel<<<blocks_e, THREADS, 0, stream>>>(
        nodef, edgef, eidx, w_m1, b_m1, w_m2, b_m2, agg, n_edges, n_nodes);

    const int groups_n = (n_nodes + EPG - 1) / EPG;
    const int blocks_n = (groups_n + WPB - 1) / WPB;
    node_mlp_tiled<<<blocks_n, THREADS, 0, stream>>>(
        nodef, agg, w_u1, b_u1, w_u2, b_u2, out, n_nodes);

    hipError_t le = hipGetLastError();
    fprintf(stderr, "[KL] last=%d(%s)\n", (int)le, hipGetErrorName(le));
    fflush(stderr);
}